// Round 13
// baseline (1458.558 us; speedup 1.0000x reference)
//
#include <hip/hip_runtime.h>

// ---------------------------------------------------------------------------
// TLSTM  (B=256, T=256, D=256, H=512)
// Persistent-scan, R12 = R9 protocol + IN-FRAGMENT fused elementwise.
//   grid = 256 WGs x 256 thr (1 WG/CU). WG (g,cs): g=bid&15 owns batch rows
//   [g*16,+16), cs=bid>>4 owns h-cols [cs*32,+32).
//   Waves: nt=wave>>1 selects the 16-col N-tile; p=wave&1 the publish row
//   half. EACH wave computes ALL 4 U-gates (B-frags in 256 VGPR) + decomp
//   (Wd from LDS) + 4 xprojs for its N-tile -> gate math runs directly on
//   the MFMA accumulator fragments (col=lane&15, row=(lane>>4)*4+j).
//   Eliminates: Z LDS tiles, the Z round trip, one barrier (2/step now).
//   Publish ~800cy earlier per step -> less consumer retry next step.
//   Waves pair-duplicate compute; publish split by row half (p).
//   Exchange: u32 per (row,col) = [h(bf16)|c(bf16)], 2-bit step tag in the
//   LSBs of both halves (mask 0x00010001 — same check as R9), sc0sc1,
//   selective retry with guard. Memset-zero == tag of t=-1. Math order
//   bitwise-identical to R9 (absmax must stay exactly 1.2207e-4).
// ---------------------------------------------------------------------------

#define T_STEPS 256
#define BATCH   256
#define DIN     256
#define HID     512

typedef __attribute__((ext_vector_type(8))) __bf16 bf16x8;
typedef __attribute__((ext_vector_type(4))) float  f32x4;

#define MFMA(a,b,c) __builtin_amdgcn_mfma_f32_16x16x32_bf16((a),(b),(c),0,0,0)

// LDS layout (byte offsets).
#define H_S     0            // 16 x 1040B
#define C_S     16640        // 16 x 1040B
#define X_S     33280        // 16 x 528B
#define WIN_S   41728        // 4 gates x 32 cols x 528B = 67584
#define WD_S    109312       // 32 cols x 1040B = 33280
#define LDS_SZ  142592
#define HSTR    1040
#define XSTR    528

struct ScanP {
  const float *x, *tim;
  const float *Wi_w,*Wi_b,*Ui_w,*Ui_b,*bi;
  const float *Wf_w,*Wf_b,*Uf_w,*Uf_b,*bf_;
  const float *Wo_w,*Wo_b,*Uo_w,*Uo_b,*bo;
  const float *Wc_w,*Wc_b,*Uc_w,*Uc_b,*bc;
  const float *Wd_w,*b_dec;
  unsigned int *hc_buf;            // [2][256 rows][512 cols] u32 = [h|c]
  float *h_final;                  // [256][512] fp32
};

__device__ __forceinline__ float fsigm(float z){ return 1.f/(1.f + __expf(-z)); }
__device__ __forceinline__ float ftanh(float z){
  float e = __expf(-2.f*fabsf(z));
  float t = (1.f - e)/(1.f + e);
  return z < 0.f ? -t : t;
}

// device-coherent via MALL (bypass non-coherent L1+L2) — R3..R9 proven path
__device__ __forceinline__ uint4 cld16(const void* p){
  uint4 r;
  asm volatile("global_load_dwordx4 %0, %1, off sc0 sc1"
               : "=v"(r) : "v"(p) : "memory");
  return r;
}
__device__ __forceinline__ void cst4(void* p, unsigned int v){
  asm volatile("global_store_dword %0, %1, off sc0 sc1"
               :: "v"(p), "v"(v) : "memory");
}

__device__ __forceinline__ bf16x8 wfrag8(const float* p){
  const float4* p4 = (const float4*)p;
  float4 a = p4[0], b = p4[1];
  bf16x8 r = { (__bf16)a.x,(__bf16)a.y,(__bf16)a.z,(__bf16)a.w,
               (__bf16)b.x,(__bf16)b.y,(__bf16)b.z,(__bf16)b.w };
  return r;
}

__global__ void __launch_bounds__(256, 1) tlstm_scan(ScanP P)
{
  __shared__ __align__(16) char L[LDS_SZ];
  const int tid  = threadIdx.x;
  const int bid  = blockIdx.x;
  const int g    = bid & 15;         // row group (16 groups x 16 rows)
  const int cs   = bid >> 4;         // col slice (16 slices x 32 cols)
  const int rbase = g * 16;
  const int cbase = cs * 32;
  const int wave = tid >> 6, lane = tid & 63, lo = lane & 15, hi = lane >> 4;
  const int nt   = wave >> 1;        // N-tile (16 cols) of this wave
  const int p    = wave & 1;         // publish row-half

  // ---- one-time: Win slices (4 gates x 32 cols x 256) fp32 -> bf16 -> LDS
  {
    const float* Wg = (wave == 0) ? P.Wi_w : (wave == 1) ? P.Wf_w
                    : (wave == 2) ? P.Wo_w : P.Wc_w;
    const int wc = lane >> 1, q2 = lane & 1;
    const float4* src = (const float4*)(Wg + (size_t)(cbase + wc) * DIN + q2 * 128);
    char* dst = L + WIN_S + (size_t)(wave * 32 + wc) * XSTR + q2 * 256;
#pragma unroll
    for (int j = 0; j < 16; j++){
      float4 a = src[2*j], b = src[2*j+1];
      bf16x8 o = { (__bf16)a.x,(__bf16)a.y,(__bf16)a.z,(__bf16)a.w,
                   (__bf16)b.x,(__bf16)b.y,(__bf16)b.z,(__bf16)b.w };
      *(bf16x8*)(dst + j*16) = o;
    }
  }
  // ---- one-time: Wd slice (32 cols x 512) fp32 -> bf16 -> LDS [col][K]
  {
    const int col = tid >> 3, seg = tid & 7;          // 64 f32 per (col,seg)
    const float4* src = (const float4*)(P.Wd_w + (size_t)(cbase + col) * HID + seg * 64);
    char* dst = L + WD_S + (size_t)col * 1040 + seg * 128;
#pragma unroll
    for (int j = 0; j < 8; j++){
      float4 a = src[2*j], b = src[2*j+1];
      bf16x8 o = { (__bf16)a.x,(__bf16)a.y,(__bf16)a.z,(__bf16)a.w,
                   (__bf16)b.x,(__bf16)b.y,(__bf16)b.z,(__bf16)b.w };
      *(bf16x8*)(dst + j*16) = o;
    }
  }

  // ---- one-time: ALL FOUR U-gate B-fragments -> registers (loop-invariant)
  bf16x8 bUi[16], bUf[16], bUo[16], bUc[16];
  {
    const size_t colb = (size_t)(cbase + nt * 16 + lo) * HID;
#pragma unroll
    for (int kc = 0; kc < 16; kc++){
      bUi[kc] = wfrag8(P.Ui_w + colb + kc * 32 + hi * 8);
      bUf[kc] = wfrag8(P.Uf_w + colb + kc * 32 + hi * 8);
      bUo[kc] = wfrag8(P.Uo_w + colb + kc * 32 + hi * 8);
      bUc[kc] = wfrag8(P.Uc_w + colb + kc * 32 + hi * 8);
    }
  }

  // ---- per-lane elementwise identity: col = colg, rows rb4+0..3
  const int colg = cbase + nt * 16 + (lane & 15);
  const int rb4  = (lane >> 4) * 4;
  const int pub_on = ((lane >> 5) == p);   // this lane's rows in my half?
  float Bi = P.Wi_b[colg] + P.bi[colg]  + P.Ui_b[colg];
  float Bf = P.Wf_b[colg] + P.bf_[colg] + P.Uf_b[colg];
  float Bo = P.Wo_b[colg] + P.bo[colg]  + P.Uo_b[colg];
  float Bc = P.Wc_b[colg] + P.bc[colg]  + P.Uc_b[colg];
  float Bd = P.b_dec[colg];
  f32x4 cr = {0.f, 0.f, 0.f, 0.f};

  const int srow = tid >> 4, sseg = tid & 15;   // x staging map (16x16)

  __syncthreads();   // Win/Wd staged before first use

#pragma unroll 1
  for (int t = 0; t < T_STEPS; ++t){
    const int rp = t & 1;
    const char* hcprevB = (const char*)(P.hc_buf + (size_t)rp * BATCH * HID);
    char* hcnextB = (char*)(P.hc_buf + (size_t)(rp ^ 1) * BATCH * HID);

    // x slice + tim (independent of peers): issue early (plain cached loads)
    const float4* xsrc = (const float4*)(P.x + ((size_t)(rbase + srow) * T_STEPS + t) * DIN + sseg * 16);
    float4 xv[4];
#pragma unroll
    for (int j = 0; j < 4; j++) xv[j] = xsrc[j];
    float tmv[4];
#pragma unroll
    for (int j = 0; j < 4; j++)
      tmv[j] = P.tim[(size_t)(rbase + rb4 + j) * T_STEPS + t];

    // ---- issue all h/c coherent loads (8 x dwordx4 per thread, in flight)
    uint4 gr[8];
    const char* src = hcprevB + (size_t)(rbase + wave * 4) * 2048;
#pragma unroll
    for (int j = 0; j < 8; j++){
      int row = j >> 1;                       // within this wave's 4 rows
      int Lg  = (j & 1) * 64 + lane;          // u32-quad index within row
      gr[j] = cld16(src + (size_t)row * 2048 + (size_t)Lg * 16);
    }

    // ---- stage x (fp32 -> bf16) — fills the h/c load shadow
    {
      char* dst = L + X_S + srow * XSTR + sseg * 32;
#pragma unroll
      for (int j = 0; j < 2; j++){
        float4 a = xv[2*j], b = xv[2*j+1];
        bf16x8 o = { (__bf16)a.x,(__bf16)a.y,(__bf16)a.z,(__bf16)a.w,
                     (__bf16)b.x,(__bf16)b.y,(__bf16)b.z,(__bf16)b.w };
        *(bf16x8*)(dst + j*16) = o;
      }
    }

    asm volatile("s_waitcnt vmcnt(0)" ::: "memory");
    __builtin_amdgcn_sched_barrier(0);

    // ---- validate tags; selective retry (guarded). Every u32 = [h|c] with
    //      tag bit0 at bit16 (h LSB) and bit1 at bit0 (c LSB).
    {
      const unsigned int expv = ((unsigned int)(t & 1) << 16)
                              |  (unsigned int)((t >> 1) & 1);
      unsigned int stale = 0;
#pragma unroll
      for (int j = 0; j < 8; j++){
        unsigned int bad = ((gr[j].x ^ expv) | (gr[j].y ^ expv)
                          | (gr[j].z ^ expv) | (gr[j].w ^ expv)) & 0x00010001u;
        stale |= (bad ? 1u : 0u) << j;
      }
      int guard = 0;
      while (__any((int)stale) && ++guard < 65536){
#pragma unroll
        for (int j = 0; j < 8; j++){
          if (stale & (1u << j)){
            int row = j >> 1;
            int Lg  = (j & 1) * 64 + lane;
            gr[j] = cld16(src + (size_t)row * 2048 + (size_t)Lg * 16);
          }
        }
        asm volatile("s_waitcnt vmcnt(0)" ::: "memory");
        __builtin_amdgcn_sched_barrier(0);
        unsigned int ns = 0;
#pragma unroll
        for (int j = 0; j < 8; j++){
          if (stale & (1u << j)){
            unsigned int bad = ((gr[j].x ^ expv) | (gr[j].y ^ expv)
                              | (gr[j].z ^ expv) | (gr[j].w ^ expv)) & 0x00010001u;
            ns |= (bad ? 1u : 0u) << j;
          }
        }
        stale = ns;
      }
    }

    // ---- commit h/c to LDS (unpack [h|c] u32 quads -> bf16 rows)
    {
#pragma unroll
      for (int j = 0; j < 8; j++){
        int row = wave * 4 + (j >> 1);
        int Lg  = (j & 1) * 64 + lane;
        uint2 hp = { (gr[j].x >> 16) | (gr[j].y & 0xffff0000u),
                     (gr[j].z >> 16) | (gr[j].w & 0xffff0000u) };
        uint2 cp = { (gr[j].x & 0xffffu) | (gr[j].y << 16),
                     (gr[j].z & 0xffffu) | (gr[j].w << 16) };
        *(uint2*)(L + H_S + row * HSTR + Lg * 8) = hp;
        *(uint2*)(L + C_S + row * HSTR + Lg * 8) = cp;
      }
    }
    __syncthreads();   // B1: X/H/C staged

    // ---- MFMA: this wave does EVERYTHING for its 16 cols
    f32x4 zi_ = {0.f,0.f,0.f,0.f}, zf_ = zi_, zo_ = zi_, zc_ = zi_, zd_ = zi_;
    f32x4 xi_ = zi_, xf_ = zi_, xo_ = zi_, xc_ = zi_;
#pragma unroll
    for (int kc = 0; kc < 16; kc++){
      bf16x8 a = *(const bf16x8*)(L + H_S + lo * HSTR + kc*64 + hi*16);
      zi_ = MFMA(a, bUi[kc], zi_);
      zf_ = MFMA(a, bUf[kc], zf_);
      zo_ = MFMA(a, bUo[kc], zo_);
      zc_ = MFMA(a, bUc[kc], zc_);
    }
#pragma unroll
    for (int kc = 0; kc < 16; kc++){
      bf16x8 a  = *(const bf16x8*)(L + C_S + lo * HSTR + kc*64 + hi*16);
      bf16x8 wd = *(const bf16x8*)(L + WD_S + (size_t)(nt*16 + lo) * 1040 + kc*64 + hi*16);
      zd_ = MFMA(a, wd, zd_);
    }
#pragma unroll
    for (int q = 0; q < 8; q++){
      bf16x8 ax = *(const bf16x8*)(L + X_S + lo * XSTR + q*64 + hi*16);
      bf16x8 w0 = *(const bf16x8*)(L + WIN_S + (size_t)(0*32 + nt*16 + lo) * XSTR + q*64 + hi*16);
      bf16x8 w1 = *(const bf16x8*)(L + WIN_S + (size_t)(1*32 + nt*16 + lo) * XSTR + q*64 + hi*16);
      bf16x8 w2 = *(const bf16x8*)(L + WIN_S + (size_t)(2*32 + nt*16 + lo) * XSTR + q*64 + hi*16);
      bf16x8 w3 = *(const bf16x8*)(L + WIN_S + (size_t)(3*32 + nt*16 + lo) * XSTR + q*64 + hi*16);
      xi_ = MFMA(ax, w0, xi_);
      xf_ = MFMA(ax, w1, xf_);
      xo_ = MFMA(ax, w2, xo_);
      xc_ = MFMA(ax, w3, xc_);
    }

    // ---- elementwise IN-FRAGMENT (no Z, no extra barrier); publish tagged u32
    {
      const unsigned int e0n = (unsigned int)((t + 1) & 1);
      const unsigned int e1n = (unsigned int)(((t + 1) >> 1) & 1);
#pragma unroll
      for (int j = 0; j < 4; j++){
        float zi = zi_[j] + xi_[j] + Bi;
        float zf = zf_[j] + xf_[j] + Bf;
        float zo = zo_[j] + xo_[j] + Bo;
        float zc = zc_[j] + xc_[j] + Bc;
        float zdv = zd_[j] + Bd;
        float Tmap = 1.f / __logf(tmv[j] + 2.7183f);
        float cst = ftanh(zdv);
        float c1  = cr[j] - cst + Tmap * cst;
        float ig = fsigm(zi), fg = fsigm(zf), og = fsigm(zo);
        float ch = ftanh(zc);
        float c2 = fg * c1 + ig * ch;
        float hv = og * ftanh(c2);
        cr[j] = c2;
        if (t < T_STEPS - 1){
          if (pub_on){
            unsigned int hb = (unsigned int)__builtin_bit_cast(unsigned short, (__bf16)hv);
            unsigned int cb = (unsigned int)__builtin_bit_cast(unsigned short, (__bf16)c2);
            unsigned int w = (((hb & 0xFFFEu) | e0n) << 16)
                           |  ((cb & 0xFFFEu) | e1n);
            cst4(hcnextB + (size_t)(rbase + rb4 + j) * 2048 + (size_t)colg * 4, w);
          }
        } else if (pub_on){
          P.h_final[(size_t)(rbase + rb4 + j) * HID + colg] = hv;
        }
      }
    }
    __syncthreads();   // tail: all LDS reads of step t done before restage
  }
}

// ---------------- head: out = relu(hT @ fc_w^T + fc_b) @ cls_w^T + cls_b ----
__global__ void __launch_bounds__(256) tlstm_head(const float* __restrict__ hfin,
    const float* __restrict__ fc_w, const float* __restrict__ fc_b,
    const float* __restrict__ cls_w, const float* __restrict__ cls_b,
    float* __restrict__ out)
{
  __shared__ float hrow[512];
  __shared__ float fcv[256];
  const int b = blockIdx.x, tid = threadIdx.x;
  ((float2*)hrow)[tid] = ((const float2*)(hfin + (size_t)b * 512))[tid];
  __syncthreads();
  {
    const float4* w4 = (const float4*)(fc_w + (size_t)tid * 512);
    const float4* h4 = (const float4*)hrow;
    float acc = fc_b[tid];
#pragma unroll 4
    for (int k = 0; k < 128; k++){
      float4 w = w4[k], h = h4[k];
      acc += w.x*h.x + w.y*h.y + w.z*h.z + w.w*h.w;
    }
    fcv[tid] = fmaxf(acc, 0.f);
  }
  __syncthreads();
  const int wave = tid >> 6, lane = tid & 63;
  if (wave < 2){
    const float* cw = cls_w + wave * 256;
    float s = 0.f;
#pragma unroll
    for (int j = lane; j < 256; j += 64) s += fcv[j] * cw[j];
#pragma unroll
    for (int off = 32; off > 0; off >>= 1) s += __shfl_down(s, off, 64);
    if (lane == 0) out[b * 2 + wave] = s + cls_b[wave];
  }
}

// ---------------------------------------------------------------------------
extern "C" void kernel_launch(void* const* d_in, const int* in_sizes, int n_in,
                              void* d_out, int out_size, void* d_ws, size_t ws_size,
                              hipStream_t stream)
{
  (void)in_sizes; (void)n_in; (void)out_size; (void)ws_size;

  ScanP P;
  P.x    = (const float*)d_in[0];
  P.tim  = (const float*)d_in[1];
  P.Wi_w = (const float*)d_in[2];  P.Wi_b = (const float*)d_in[3];
  P.Ui_w = (const float*)d_in[4];  P.Ui_b = (const float*)d_in[5];  P.bi  = (const float*)d_in[6];
  P.Wf_w = (const float*)d_in[7];  P.Wf_b = (const float*)d_in[8];
  P.Uf_w = (const float*)d_in[9];  P.Uf_b = (const float*)d_in[10]; P.bf_ = (const float*)d_in[11];
  P.Wo_w = (const float*)d_in[12]; P.Wo_b = (const float*)d_in[13];
  P.Uo_w = (const float*)d_in[14]; P.Uo_b = (const float*)d_in[15]; P.bo  = (const float*)d_in[16];
  P.Wc_w = (const float*)d_in[17]; P.Wc_b = (const float*)d_in[18];
  P.Uc_w = (const float*)d_in[19]; P.Uc_b = (const float*)d_in[20]; P.bc  = (const float*)d_in[21];
  P.Wd_w = (const float*)d_in[22]; P.b_dec = (const float*)d_in[23];
  const float* fc_w  = (const float*)d_in[24];
  const float* fc_b  = (const float*)d_in[25];
  const float* cls_w = (const float*)d_in[26];
  const float* cls_b = (const float*)d_in[27];

  // workspace layout: [hc_buf 2x512K u32][h_final 512K]
  unsigned int* hc_buf = (unsigned int*)d_ws;                    // 2*256*512 u32
  float* h_final = (float*)(hc_buf + 2 * BATCH * HID);           // 256*512 f32
  P.hc_buf = hc_buf; P.h_final = h_final;

  // zero hc (tag bits 0 == tag of t=-1; payload h=c=0)
  hipMemsetAsync(d_ws, 0, (size_t)2 * BATCH * HID * 4, stream);

  hipLaunchKernelGGL(tlstm_scan, dim3(256), dim3(256), 0, stream, P);
  hipLaunchKernelGGL(tlstm_head, dim3(256), dim3(256), 0, stream,
                     h_final, fc_w, fc_b, cls_w, cls_b, (float*)d_out);
}

// Round 14
// 904.878 us; speedup vs baseline: 1.6119x; 1.6119x over previous
//
#include <hip/hip_runtime.h>

// ---------------------------------------------------------------------------
// TLSTM  (B=256, T=256, D=256, H=512)
// Persistent-scan, R13 = R9 base + three skew-targeted deltas:
//   1) h/c load issue DELAYED until after xproj (stale-common theory: by
//      then producers have published -> first-shot load fresh, saves the
//      wasted RT that made R11 null).
//   2) x/tim prefetched one step ahead in carried registers, issued AFTER
//      the step's last asm vmcnt(0) (no drain interference, no counted
//      vmcnt) -> cold-HBM x latency leaves the chain; consumed at next
//      step's stage with a ~free compiler wait.
//   3) tail barrier dropped (audit: X writes vs xproj reads: B1/B2 between;
//      Z writes vs EW reads: B0 between; H/C writes vs U-GEMM reads: B2/B0).
//   Step: stage x(t) [carried regs] -> B0 -> xproj MFMA (Z10-17) ->
//   issue h/c + vmcnt(0) + validate + selective retry -> prefetch x(t+1) ->
//   commit h/c -> B1 -> U-GEMM+decomp (Z0-9) -> B2 -> EW + tagged publish.
//   Exchange protocol (tagged u64, 2-bit tag in every dword LSB, sc0sc1,
//   guarded selective retry) is R8/R9 verbatim. Math order unchanged.
// ---------------------------------------------------------------------------

#define T_STEPS 256
#define BATCH   256
#define DIN     256
#define HID     512

typedef __attribute__((ext_vector_type(8))) __bf16 bf16x8;
typedef __attribute__((ext_vector_type(4))) float  f32x4;

#define MFMA(a,b,c) __builtin_amdgcn_mfma_f32_16x16x32_bf16((a),(b),(c),0,0,0)

// LDS layout (byte offsets).
#define H_S     0            // 16 x 1040B
#define C_S     16640        // 16 x 1040B
#define X_S     33280        // 16 x 528B
#define WIN_S   41728        // 4 gates x 32 cols x 528B = 67584
#define Z_S     109312       // 18 tiles x 16x17 f32 = 19584
#define LDS_SZ  128896
#define HSTR    1040
#define XSTR    528
#define ZROW    17
// Z tile ids: U gate g at N-tile nt = g*2+nt (0..7); decomp = 8+nt;
//             xproj gate g at nt = 10+g*2+nt (10..17)

struct ScanP {
  const float *x, *tim;
  const float *Wi_w,*Wi_b,*Ui_w,*Ui_b,*bi;
  const float *Wf_w,*Wf_b,*Uf_w,*Uf_b,*bf_;
  const float *Wo_w,*Wo_b,*Uo_w,*Uo_b,*bo;
  const float *Wc_w,*Wc_b,*Uc_w,*Uc_b,*bc;
  const float *Wd_w,*b_dec;
  unsigned long long *hc_buf;      // [2][256 rows][256 col-pairs] u64
  float *h_final;                  // [256][512] fp32
  unsigned int *flags;             // kept in ws layout; unused
};

__device__ __forceinline__ float fsigm(float z){ return 1.f/(1.f + __expf(-z)); }
__device__ __forceinline__ float ftanh(float z){
  float e = __expf(-2.f*fabsf(z));
  float t = (1.f - e)/(1.f + e);
  return z < 0.f ? -t : t;
}

// device-coherent via MALL (bypass non-coherent L1+L2) — R3..R9 proven path
__device__ __forceinline__ uint4 cld16(const void* p){
  uint4 r;
  asm volatile("global_load_dwordx4 %0, %1, off sc0 sc1"
               : "=v"(r) : "v"(p) : "memory");
  return r;
}
__device__ __forceinline__ void cst8(void* p, unsigned long long v){
  asm volatile("global_store_dwordx2 %0, %1, off sc0 sc1"
               :: "v"(p), "v"(v) : "memory");
}

__device__ __forceinline__ bf16x8 wfrag8(const float* p){
  const float4* p4 = (const float4*)p;
  float4 a = p4[0], b = p4[1];
  bf16x8 r = { (__bf16)a.x,(__bf16)a.y,(__bf16)a.z,(__bf16)a.w,
               (__bf16)b.x,(__bf16)b.y,(__bf16)b.z,(__bf16)b.w };
  return r;
}
__device__ __forceinline__ void zstore(char* L, int tile, int lane, f32x4 v){
  float* p = (float*)(L + Z_S) + tile*(16*ZROW) + ((lane>>4)*4)*ZROW + (lane&15);
  p[0]=v[0]; p[ZROW]=v[1]; p[2*ZROW]=v[2]; p[3*ZROW]=v[3];
}
__device__ __forceinline__ float zread(const char* L, int tile, int r, int c){
  return ((const float*)(L + Z_S))[tile*(16*ZROW) + r*ZROW + c];
}

__global__ void __launch_bounds__(256, 1) tlstm_scan(ScanP P)
{
  __shared__ __align__(16) char L[LDS_SZ];
  const int tid  = threadIdx.x;
  const int bid  = blockIdx.x;
  const int g    = bid & 15;         // row group (16 groups x 16 rows)
  const int cs   = bid >> 4;         // col slice (16 slices x 32 cols)
  const int rbase = g * 16;
  const int cbase = cs * 32;
  const int wave = tid >> 6, lane = tid & 63, lo = lane & 15, hi = lane >> 4;
  const int nt   = wave & 1;         // N-tile within the 32-col slice
  const int gp   = wave >> 1;        // gate pair: 0 -> {i,f}, 1 -> {o,c}
  const int g0   = gp * 2, g1 = g0 + 1;

  // ---- one-time: Win slices (4 gates x 32 cols x 256) fp32 -> bf16 -> LDS
  {
    const float* Wg = (wave == 0) ? P.Wi_w : (wave == 1) ? P.Wf_w
                    : (wave == 2) ? P.Wo_w : P.Wc_w;
    const int wc = lane >> 1, q2 = lane & 1;
    const float4* src = (const float4*)(Wg + (size_t)(cbase + wc) * DIN + q2 * 128);
    char* dst = L + WIN_S + (size_t)(wave * 32 + wc) * XSTR + q2 * 256;
#pragma unroll
    for (int j = 0; j < 16; j++){
      float4 a = src[2*j], b = src[2*j+1];
      bf16x8 o = { (__bf16)a.x,(__bf16)a.y,(__bf16)a.z,(__bf16)a.w,
                   (__bf16)b.x,(__bf16)b.y,(__bf16)b.z,(__bf16)b.w };
      *(bf16x8*)(dst + j*16) = o;
    }
  }

  // ---- one-time: U/Wd B-fragments -> registers (loop-invariant)
  bf16x8 bP[16], bQ[16], bR[16];
  {
    const float* Pw = (gp == 0) ? P.Ui_w : P.Uo_w;
    const float* Qw = (gp == 0) ? P.Uf_w : P.Uc_w;
    const size_t colb = (size_t)(cbase + nt * 16 + lo) * HID;
#pragma unroll
    for (int kc = 0; kc < 16; kc++){
      bP[kc] = wfrag8(Pw + colb + kc * 32 + hi * 8);
      bQ[kc] = wfrag8(Qw + colb + kc * 32 + hi * 8);
    }
    if (wave >= 2){
#pragma unroll
      for (int kc = 0; kc < 16; kc++)
        bR[kc] = wfrag8(P.Wd_w + colb + kc * 32 + hi * 8);
    }
  }

  // ---- per-thread elementwise ownership: erow=tid>>4, cols cbase+(tid&15)*2
  const int erow = tid >> 4;
  const int ecp  = (tid & 15) * 2;
  float bias_i[2], bias_f[2], bias_o[2], bias_c[2], bias_d[2], cr[2];
#pragma unroll
  for (int e = 0; e < 2; e++){
    int c = cbase + ecp + e;
    bias_i[e] = P.Wi_b[c] + P.bi[c]  + P.Ui_b[c];
    bias_f[e] = P.Wf_b[c] + P.bf_[c] + P.Uf_b[c];
    bias_o[e] = P.Wo_b[c] + P.bo[c]  + P.Uo_b[c];
    bias_c[e] = P.Wc_b[c] + P.bc[c]  + P.Uc_b[c];
    bias_d[e] = P.b_dec[c];
    cr[e] = 0.f;
  }

  const int srow = tid >> 4, sseg = tid & 15;   // x staging map (16x16)
  const size_t pub_off = ((size_t)(rbase + erow) * 256 + cs * 16 + (tid & 15)) * 8;

  __syncthreads();   // Win staged before first use

  // ---- prologue: issue x(0)/tim(0) into carried regs (compiler loads)
  float4 xv[4];
  float tvr;
  {
    const float4* xs = (const float4*)(P.x + ((size_t)(rbase + srow) * T_STEPS) * DIN + sseg * 16);
#pragma unroll
    for (int j = 0; j < 4; j++) xv[j] = xs[j];
    tvr = P.tim[(size_t)(rbase + erow) * T_STEPS];
  }

#pragma unroll 1
  for (int t = 0; t < T_STEPS; ++t){
    const int rp = t & 1;
    const char* hcprev = (const char*)(P.hc_buf + (size_t)rp * BATCH * 256);
    char* hcnext = (char*)(P.hc_buf + (size_t)(rp ^ 1) * BATCH * 256);

    // ---- stage x(t) from carried regs (compiler wait, ~free after t=0)
    const float tv = tvr;
    {
      char* dst = L + X_S + srow * XSTR + sseg * 32;
#pragma unroll
      for (int j = 0; j < 2; j++){
        float4 a = xv[2*j], b = xv[2*j+1];
        bf16x8 o = { (__bf16)a.x,(__bf16)a.y,(__bf16)a.z,(__bf16)a.w,
                     (__bf16)b.x,(__bf16)b.y,(__bf16)b.z,(__bf16)b.w };
        *(bf16x8*)(dst + j*16) = o;
      }
    }
    __syncthreads();   // B0: X staged

    // ---- xproj MFMA (X + Win only) — covers producer publish lag
    f32x4 xA = {0.f,0.f,0.f,0.f}, xB = xA;
#pragma unroll
    for (int q = 0; q < 8; q++){
      bf16x8 ax = *(const bf16x8*)(L + X_S + lo * XSTR + q*64 + hi*16);
      bf16x8 w0 = *(const bf16x8*)(L + WIN_S + (size_t)(g0*32 + nt*16 + lo) * XSTR + q*64 + hi*16);
      bf16x8 w1 = *(const bf16x8*)(L + WIN_S + (size_t)(g1*32 + nt*16 + lo) * XSTR + q*64 + hi*16);
      xA = MFMA(ax, w0, xA);
      xB = MFMA(ax, w1, xB);
    }
    zstore(L, 10+g0*2+nt, lane, xA);
    zstore(L, 10+g1*2+nt, lane, xB);

    // ---- NOW issue h/c loads (delayed: producers likely published)
    uint4 gr[8];
    const char* src = hcprev + (size_t)(rbase + wave * 4) * 2048;
#pragma unroll
    for (int j = 0; j < 8; j++){
      int row = j >> 1;                       // within this wave's 4 rows
      int gg  = (j & 1) * 64 + lane;          // 16B granule within row
      gr[j] = cld16(src + (size_t)row * 2048 + (size_t)gg * 16);
    }
    asm volatile("s_waitcnt vmcnt(0)" ::: "memory");
    __builtin_amdgcn_sched_barrier(0);

    // ---- validate tags; selective retry (R8/R9 verbatim, 8 entries)
    {
      const unsigned int expv = (unsigned int)(t & 1)
                              | ((unsigned int)((t >> 1) & 1) << 16);
      unsigned int stale = 0;
#pragma unroll
      for (int j = 0; j < 8; j++){
        unsigned int bad = ((gr[j].x ^ expv) | (gr[j].y ^ expv)
                          | (gr[j].z ^ expv) | (gr[j].w ^ expv)) & 0x00010001u;
        stale |= (bad ? 1u : 0u) << j;
      }
      int guard = 0;
      while (__any((int)stale) && ++guard < 65536){
#pragma unroll
        for (int j = 0; j < 8; j++){
          if (stale & (1u << j)){
            int row = j >> 1;
            int gg  = (j & 1) * 64 + lane;
            gr[j] = cld16(src + (size_t)row * 2048 + (size_t)gg * 16);
          }
        }
        asm volatile("s_waitcnt vmcnt(0)" ::: "memory");
        __builtin_amdgcn_sched_barrier(0);
        unsigned int ns = 0;
#pragma unroll
        for (int j = 0; j < 8; j++){
          if (stale & (1u << j)){
            unsigned int bad = ((gr[j].x ^ expv) | (gr[j].y ^ expv)
                              | (gr[j].z ^ expv) | (gr[j].w ^ expv)) & 0x00010001u;
            ns |= (bad ? 1u : 0u) << j;
          }
        }
        stale = ns;
      }
    }

    // ---- prefetch x(t+1)/tim(t+1) into carried regs (after last asm drain;
    //      flies across B1 + U-GEMM + B2 + EW, consumed next step ~free)
    if (t < T_STEPS - 1){
      const float4* xs = (const float4*)(P.x + ((size_t)(rbase + srow) * T_STEPS + (t + 1)) * DIN + sseg * 16);
#pragma unroll
      for (int j = 0; j < 4; j++) xv[j] = xs[j];
      tvr = P.tim[(size_t)(rbase + erow) * T_STEPS + (t + 1)];
    }

    // ---- commit h/c to LDS. gr = [h01,c01,h23,c23] -> h {x,z}, c {y,w}
    {
#pragma unroll
      for (int j = 0; j < 8; j++){
        int row = wave * 4 + (j >> 1);
        int gg  = (j & 1) * 64 + lane;
        *(uint2*)(L + H_S + row * HSTR + gg * 8) = uint2{gr[j].x, gr[j].z};
        *(uint2*)(L + C_S + row * HSTR + gg * 8) = uint2{gr[j].y, gr[j].w};
      }
    }
    __syncthreads();   // B1: H/C committed

    // ---- U-GEMM + decomp MFMA (needs committed H/C)
    {
      f32x4 zA = {0.f,0.f,0.f,0.f}, zB = zA, zD = zA;
#pragma unroll
      for (int kc = 0; kc < 16; kc++){
        bf16x8 a = *(const bf16x8*)(L + H_S + lo * HSTR + kc*64 + hi*16);
        zA = MFMA(a, bP[kc], zA);
        zB = MFMA(a, bQ[kc], zB);
      }
      if (wave >= 2){
#pragma unroll
        for (int kc = 0; kc < 16; kc++){
          bf16x8 a = *(const bf16x8*)(L + C_S + lo * HSTR + kc*64 + hi*16);
          zD = MFMA(a, bR[kc], zD);
        }
      }
      zstore(L, g0*2+nt, lane, zA);
      zstore(L, g1*2+nt, lane, zB);
      if (wave >= 2) zstore(L, 8+nt, lane, zD);
    }
    __syncthreads();   // B2: all Z tiles ready

    // ---- elementwise gate math (fp32); publish tagged u64
    {
      float Tmap = 1.f / __logf(tv + 2.7183f);
      unsigned int hpk = 0, cpk = 0;
      float hv2[2];
#pragma unroll
      for (int e = 0; e < 2; e++){
        int col = ecp + e;
        int ntc = col >> 4, cl = col & 15;
        float zi = zread(L, 0+ntc,  erow, cl) + zread(L, 10+0+ntc,  erow, cl) + bias_i[e];
        float zf = zread(L, 2+ntc,  erow, cl) + zread(L, 10+2+ntc,  erow, cl) + bias_f[e];
        float zo = zread(L, 4+ntc,  erow, cl) + zread(L, 10+4+ntc,  erow, cl) + bias_o[e];
        float zc = zread(L, 6+ntc,  erow, cl) + zread(L, 10+6+ntc,  erow, cl) + bias_c[e];
        float zdv = zread(L, 8+ntc, erow, cl) + bias_d[e];
        float cst = ftanh(zdv);
        float c1  = cr[e] - cst + Tmap * cst;
        float ig = fsigm(zi), fg = fsigm(zf), og = fsigm(zo);
        float ch = ftanh(zc);
        float c2 = fg * c1 + ig * ch;
        float hv_ = og * ftanh(c2);
        cr[e] = c2; hv2[e] = hv_;
        hpk |= (unsigned int)__builtin_bit_cast(unsigned short, (__bf16)hv_) << (16*e);
        cpk |= (unsigned int)__builtin_bit_cast(unsigned short, (__bf16)c2) << (16*e);
      }
      if (t < T_STEPS - 1){
        const unsigned int wtag  = (unsigned int)((t + 1) & 3);
        const unsigned int tmask = (wtag & 1u) | ((wtag >> 1) << 16);
        hpk = (hpk & 0xFFFEFFFEu) | tmask;   // full tag in both bf16 LSBs
        cpk = (cpk & 0xFFFEFFFEu) | tmask;
        cst8(hcnext + pub_off,
             (unsigned long long)hpk | ((unsigned long long)cpk << 32));
      } else {
        size_t off = (size_t)(rbase + erow) * HID + cbase + ecp;
        P.h_final[off]     = hv2[0];
        P.h_final[off + 1] = hv2[1];
      }
    }
    // (no tail barrier: X writes vs xproj reads separated by B1/B2;
    //  Z writes vs EW reads by B0; H/C writes vs U-GEMM reads by B2/B0)
  }
}

// ---------------- head: out = relu(hT @ fc_w^T + fc_b) @ cls_w^T + cls_b ----
__global__ void __launch_bounds__(256) tlstm_head(const float* __restrict__ hfin,
    const float* __restrict__ fc_w, const float* __restrict__ fc_b,
    const float* __restrict__ cls_w, const float* __restrict__ cls_b,
    float* __restrict__ out)
{
  __shared__ float hrow[512];
  __shared__ float fcv[256];
  const int b = blockIdx.x, tid = threadIdx.x;
  ((float2*)hrow)[tid] = ((const float2*)(hfin + (size_t)b * 512))[tid];
  __syncthreads();
  {
    const float4* w4 = (const float4*)(fc_w + (size_t)tid * 512);
    const float4* h4 = (const float4*)hrow;
    float acc = fc_b[tid];
#pragma unroll 4
    for (int k = 0; k < 128; k++){
      float4 w = w4[k], h = h4[k];
      acc += w.x*h.x + w.y*h.y + w.z*h.z + w.w*h.w;
    }
    fcv[tid] = fmaxf(acc, 0.f);
  }
  __syncthreads();
  const int wave = tid >> 6, lane = tid & 63;
  if (wave < 2){
    const float* cw = cls_w + wave * 256;
    float s = 0.f;
#pragma unroll
    for (int j = lane; j < 256; j += 64) s += fcv[j] * cw[j];
#pragma unroll
    for (int off = 32; off > 0; off >>= 1) s += __shfl_down(s, off, 64);
    if (lane == 0) out[b * 2 + wave] = s + cls_b[wave];
  }
}

// ---------------------------------------------------------------------------
extern "C" void kernel_launch(void* const* d_in, const int* in_sizes, int n_in,
                              void* d_out, int out_size, void* d_ws, size_t ws_size,
                              hipStream_t stream)
{
  (void)in_sizes; (void)n_in; (void)out_size; (void)ws_size;

  ScanP P;
  P.x    = (const float*)d_in[0];
  P.tim  = (const float*)d_in[1];
  P.Wi_w = (const float*)d_in[2];  P.Wi_b = (const float*)d_in[3];
  P.Ui_w = (const float*)d_in[4];  P.Ui_b = (const float*)d_in[5];  P.bi  = (const float*)d_in[6];
  P.Wf_w = (const float*)d_in[7];  P.Wf_b = (const float*)d_in[8];
  P.Uf_w = (const float*)d_in[9];  P.Uf_b = (const float*)d_in[10]; P.bf_ = (const float*)d_in[11];
  P.Wo_w = (const float*)d_in[12]; P.Wo_b = (const float*)d_in[13];
  P.Uo_w = (const float*)d_in[14]; P.Uo_b = (const float*)d_in[15]; P.bo  = (const float*)d_in[16];
  P.Wc_w = (const float*)d_in[17]; P.Wc_b = (const float*)d_in[18];
  P.Uc_w = (const float*)d_in[19]; P.Uc_b = (const float*)d_in[20]; P.bc  = (const float*)d_in[21];
  P.Wd_w = (const float*)d_in[22]; P.b_dec = (const float*)d_in[23];
  const float* fc_w  = (const float*)d_in[24];
  const float* fc_b  = (const float*)d_in[25];
  const float* cls_w = (const float*)d_in[26];
  const float* cls_b = (const float*)d_in[27];

  // workspace layout (identical to R3..R9): [hc_buf 1M][flags 1K][h_final 512K]
  unsigned long long* hc_buf = (unsigned long long*)d_ws;        // 2*256*256 u64
  unsigned int* flags = (unsigned int*)(hc_buf + 2 * BATCH * 256);
  float* h_final = (float*)((char*)flags + 1024);                // 256*512 f32
  P.hc_buf = hc_buf; P.h_final = h_final; P.flags = flags;

  const size_t zero_bytes = (size_t)2 * BATCH * 256 * 8 + 1024;  // hc + flags
  hipMemsetAsync(d_ws, 0, zero_bytes, stream);

  hipLaunchKernelGGL(tlstm_scan, dim3(256), dim3(256), 0, stream, P);
  hipLaunchKernelGGL(tlstm_head, dim3(256), dim3(256), 0, stream,
                     h_final, fc_w, fc_b, cls_w, cls_b, (float*)d_out);
}

// Round 16
// 869.052 us; speedup vs baseline: 1.6783x; 1.0412x over previous
//
#include <hip/hip_runtime.h>

// ---------------------------------------------------------------------------
// TLSTM  (B=256, T=256, D=256, H=512)
// Persistent-scan, R15 = R13 (proven, 905us) + barrier trim (3 -> 2):
//   - xproj Z tiles parity-double-buffered (Z2[t&1]) -> EW(t) reads and
//     xproj(t+1) writes never collide -> B0 eliminated.
//   - X(t+1) staging moved into the U-GEMM phase (B1..B2), ds_writes hide
//     under MFMA; x(t+1)/tim(t) issued at step TOP so the validate vmcnt(0)
//     drain finds them ~coterminal with the h/c MALL RT (no counted vmcnt).
//   Step t: issue x(t+1)+tim(t) -> xproj(t) [X from t-1] -> Z2[t&1] ->
//   issue h/c (delayed) -> vmcnt(0) -> validate + selective retry ->
//   commit h/c -> B1 -> U-GEMM+decomp (Z0-9) + stage X(t+1) -> B2 ->
//   EW (Z0-9 + Z2[t&1]) + tagged publish.
//   Exchange protocol (tagged u64, 2-bit tag in every dword LSB, sc0sc1,
//   guarded selective retry): R13 verbatim. Math order unchanged.
//   L2-scope exchange abandoned permanently (R4/R5/R14: replay-coherence).
// ---------------------------------------------------------------------------

#define T_STEPS 256
#define BATCH   256
#define DIN     256
#define HID     512

typedef __attribute__((ext_vector_type(8))) __bf16 bf16x8;
typedef __attribute__((ext_vector_type(4))) float  f32x4;

#define MFMA(a,b,c) __builtin_amdgcn_mfma_f32_16x16x32_bf16((a),(b),(c),0,0,0)

// LDS layout (byte offsets).
#define H_S     0            // 16 x 1040B
#define C_S     16640        // 16 x 1040B
#define X_S     33280        // 16 x 528B
#define WIN_S   41728        // 4 gates x 32 cols x 528B = 67584
#define Z_S     109312       // 10 tiles x 16x17 f32 = 10880 (U 0..7, dec 8,9)
#define Z2_S    120192       // 2 parity x 8 tiles x 16x17 f32 = 17408 (xproj)
#define LDS_SZ  137600
#define HSTR    1040
#define XSTR    528
#define ZROW    17
// Z tile ids: U gate g at N-tile nt = g*2+nt (0..7); decomp = 8+nt.
// Z2 tile ids (per parity): xproj gate g at nt = g*2+nt (0..7).

struct ScanP {
  const float *x, *tim;
  const float *Wi_w,*Wi_b,*Ui_w,*Ui_b,*bi;
  const float *Wf_w,*Wf_b,*Uf_w,*Uf_b,*bf_;
  const float *Wo_w,*Wo_b,*Uo_w,*Uo_b,*bo;
  const float *Wc_w,*Wc_b,*Uc_w,*Uc_b,*bc;
  const float *Wd_w,*b_dec;
  unsigned long long *hc_buf;      // [2][256 rows][256 col-pairs] u64
  float *h_final;                  // [256][512] fp32
  unsigned int *flags;             // kept in ws layout; unused
};

__device__ __forceinline__ float fsigm(float z){ return 1.f/(1.f + __expf(-z)); }
__device__ __forceinline__ float ftanh(float z){
  float e = __expf(-2.f*fabsf(z));
  float t = (1.f - e)/(1.f + e);
  return z < 0.f ? -t : t;
}

// device-coherent via MALL (bypass non-coherent L1+L2) — R3..R13 proven path
__device__ __forceinline__ uint4 cld16(const void* p){
  uint4 r;
  asm volatile("global_load_dwordx4 %0, %1, off sc0 sc1"
               : "=v"(r) : "v"(p) : "memory");
  return r;
}
__device__ __forceinline__ void cst8(void* p, unsigned long long v){
  asm volatile("global_store_dwordx2 %0, %1, off sc0 sc1"
               :: "v"(p), "v"(v) : "memory");
}

__device__ __forceinline__ bf16x8 wfrag8(const float* p){
  const float4* p4 = (const float4*)p;
  float4 a = p4[0], b = p4[1];
  bf16x8 r = { (__bf16)a.x,(__bf16)a.y,(__bf16)a.z,(__bf16)a.w,
               (__bf16)b.x,(__bf16)b.y,(__bf16)b.z,(__bf16)b.w };
  return r;
}
__device__ __forceinline__ void zstore(char* L, int tile, int lane, f32x4 v){
  float* p = (float*)(L + Z_S) + tile*(16*ZROW) + ((lane>>4)*4)*ZROW + (lane&15);
  p[0]=v[0]; p[ZROW]=v[1]; p[2*ZROW]=v[2]; p[3*ZROW]=v[3];
}
__device__ __forceinline__ float zread(const char* L, int tile, int r, int c){
  return ((const float*)(L + Z_S))[tile*(16*ZROW) + r*ZROW + c];
}
__device__ __forceinline__ void z2store(char* L, int par, int tile, int lane, f32x4 v){
  float* p = (float*)(L + Z2_S) + (par*8 + tile)*(16*ZROW) + ((lane>>4)*4)*ZROW + (lane&15);
  p[0]=v[0]; p[ZROW]=v[1]; p[2*ZROW]=v[2]; p[3*ZROW]=v[3];
}
__device__ __forceinline__ float z2read(const char* L, int par, int tile, int r, int c){
  return ((const float*)(L + Z2_S))[(par*8 + tile)*(16*ZROW) + r*ZROW + c];
}

__global__ void __launch_bounds__(256, 1) tlstm_scan(ScanP P)
{
  __shared__ __align__(16) char L[LDS_SZ];
  const int tid  = threadIdx.x;
  const int bid  = blockIdx.x;
  const int g    = bid & 15;         // row group (16 groups x 16 rows)
  const int cs   = bid >> 4;         // col slice (16 slices x 32 cols)
  const int rbase = g * 16;
  const int cbase = cs * 32;
  const int wave = tid >> 6, lane = tid & 63, lo = lane & 15, hi = lane >> 4;
  const int nt   = wave & 1;         // N-tile within the 32-col slice
  const int gp   = wave >> 1;        // gate pair: 0 -> {i,f}, 1 -> {o,c}
  const int g0   = gp * 2, g1 = g0 + 1;

  // ---- one-time: Win slices (4 gates x 32 cols x 256) fp32 -> bf16 -> LDS
  {
    const float* Wg = (wave == 0) ? P.Wi_w : (wave == 1) ? P.Wf_w
                    : (wave == 2) ? P.Wo_w : P.Wc_w;
    const int wc = lane >> 1, q2 = lane & 1;
    const float4* src = (const float4*)(Wg + (size_t)(cbase + wc) * DIN + q2 * 128);
    char* dst = L + WIN_S + (size_t)(wave * 32 + wc) * XSTR + q2 * 256;
#pragma unroll
    for (int j = 0; j < 16; j++){
      float4 a = src[2*j], b = src[2*j+1];
      bf16x8 o = { (__bf16)a.x,(__bf16)a.y,(__bf16)a.z,(__bf16)a.w,
                   (__bf16)b.x,(__bf16)b.y,(__bf16)b.z,(__bf16)b.w };
      *(bf16x8*)(dst + j*16) = o;
    }
  }

  // ---- one-time: U/Wd B-fragments -> registers (loop-invariant)
  bf16x8 bP[16], bQ[16], bR[16];
  {
    const float* Pw = (gp == 0) ? P.Ui_w : P.Uo_w;
    const float* Qw = (gp == 0) ? P.Uf_w : P.Uc_w;
    const size_t colb = (size_t)(cbase + nt * 16 + lo) * HID;
#pragma unroll
    for (int kc = 0; kc < 16; kc++){
      bP[kc] = wfrag8(Pw + colb + kc * 32 + hi * 8);
      bQ[kc] = wfrag8(Qw + colb + kc * 32 + hi * 8);
    }
    if (wave >= 2){
#pragma unroll
      for (int kc = 0; kc < 16; kc++)
        bR[kc] = wfrag8(P.Wd_w + colb + kc * 32 + hi * 8);
    }
  }

  // ---- per-thread elementwise ownership: erow=tid>>4, cols cbase+(tid&15)*2
  const int erow = tid >> 4;
  const int ecp  = (tid & 15) * 2;
  float bias_i[2], bias_f[2], bias_o[2], bias_c[2], bias_d[2], cr[2];
#pragma unroll
  for (int e = 0; e < 2; e++){
    int c = cbase + ecp + e;
    bias_i[e] = P.Wi_b[c] + P.bi[c]  + P.Ui_b[c];
    bias_f[e] = P.Wf_b[c] + P.bf_[c] + P.Uf_b[c];
    bias_o[e] = P.Wo_b[c] + P.bo[c]  + P.Uo_b[c];
    bias_c[e] = P.Wc_b[c] + P.bc[c]  + P.Uc_b[c];
    bias_d[e] = P.b_dec[c];
    cr[e] = 0.f;
  }

  const int srow = tid >> 4, sseg = tid & 15;   // x staging map (16x16)
  const size_t pub_off = ((size_t)(rbase + erow) * 256 + cs * 16 + (tid & 15)) * 8;

  // ---- prologue: load x(0) (compiler), stage X(0); barrier covers Win too
  float4 xv[4];
  {
    const float4* xs = (const float4*)(P.x + ((size_t)(rbase + srow) * T_STEPS) * DIN + sseg * 16);
#pragma unroll
    for (int j = 0; j < 4; j++) xv[j] = xs[j];
    char* dst = L + X_S + srow * XSTR + sseg * 32;
#pragma unroll
    for (int j = 0; j < 2; j++){
      float4 a = xv[2*j], b = xv[2*j+1];
      bf16x8 o = { (__bf16)a.x,(__bf16)a.y,(__bf16)a.z,(__bf16)a.w,
                   (__bf16)b.x,(__bf16)b.y,(__bf16)b.z,(__bf16)b.w };
      *(bf16x8*)(dst + j*16) = o;
    }
  }
  __syncthreads();   // Win + X(0) staged before first use

#pragma unroll 1
  for (int t = 0; t < T_STEPS; ++t){
    const int rp = t & 1;
    const int p2 = t & 1;
    const char* hcprev = (const char*)(P.hc_buf + (size_t)rp * BATCH * 256);
    char* hcnext = (char*)(P.hc_buf + (size_t)(rp ^ 1) * BATCH * 256);

    // ---- top: issue x(t+1) + tim(t) (compiler loads; drain at validate is
    //      ~coterminal with the h/c MALL RT -> no added stall)
    if (t < T_STEPS - 1){
      const float4* xs = (const float4*)(P.x + ((size_t)(rbase + srow) * T_STEPS + (t + 1)) * DIN + sseg * 16);
#pragma unroll
      for (int j = 0; j < 4; j++) xv[j] = xs[j];
    }
    const float tv = P.tim[(size_t)(rbase + erow) * T_STEPS + t];

    // ---- xproj MFMA (X from step t-1 + Win) -> Z2[t&1]; covers publish lag
    f32x4 xA = {0.f,0.f,0.f,0.f}, xB = xA;
#pragma unroll
    for (int q = 0; q < 8; q++){
      bf16x8 ax = *(const bf16x8*)(L + X_S + lo * XSTR + q*64 + hi*16);
      bf16x8 w0 = *(const bf16x8*)(L + WIN_S + (size_t)(g0*32 + nt*16 + lo) * XSTR + q*64 + hi*16);
      bf16x8 w1 = *(const bf16x8*)(L + WIN_S + (size_t)(g1*32 + nt*16 + lo) * XSTR + q*64 + hi*16);
      xA = MFMA(ax, w0, xA);
      xB = MFMA(ax, w1, xB);
    }
    z2store(L, p2, g0*2+nt, lane, xA);
    z2store(L, p2, g1*2+nt, lane, xB);

    // ---- issue h/c loads (delayed: producers likely published)
    uint4 gr[8];
    const char* src = hcprev + (size_t)(rbase + wave * 4) * 2048;
#pragma unroll
    for (int j = 0; j < 8; j++){
      int row = j >> 1;                       // within this wave's 4 rows
      int gg  = (j & 1) * 64 + lane;          // 16B granule within row
      gr[j] = cld16(src + (size_t)row * 2048 + (size_t)gg * 16);
    }
    asm volatile("s_waitcnt vmcnt(0)" ::: "memory");
    __builtin_amdgcn_sched_barrier(0);

    // ---- validate tags; selective retry (R8/R9/R13 verbatim, 8 entries)
    {
      const unsigned int expv = (unsigned int)(t & 1)
                              | ((unsigned int)((t >> 1) & 1) << 16);
      unsigned int stale = 0;
#pragma unroll
      for (int j = 0; j < 8; j++){
        unsigned int bad = ((gr[j].x ^ expv) | (gr[j].y ^ expv)
                          | (gr[j].z ^ expv) | (gr[j].w ^ expv)) & 0x00010001u;
        stale |= (bad ? 1u : 0u) << j;
      }
      int guard = 0;
      while (__any((int)stale) && ++guard < 65536){
#pragma unroll
        for (int j = 0; j < 8; j++){
          if (stale & (1u << j)){
            int row = j >> 1;
            int gg  = (j & 1) * 64 + lane;
            gr[j] = cld16(src + (size_t)row * 2048 + (size_t)gg * 16);
          }
        }
        asm volatile("s_waitcnt vmcnt(0)" ::: "memory");
        __builtin_amdgcn_sched_barrier(0);
        unsigned int ns = 0;
#pragma unroll
        for (int j = 0; j < 8; j++){
          if (stale & (1u << j)){
            unsigned int bad = ((gr[j].x ^ expv) | (gr[j].y ^ expv)
                              | (gr[j].z ^ expv) | (gr[j].w ^ expv)) & 0x00010001u;
            ns |= (bad ? 1u : 0u) << j;
          }
        }
        stale = ns;
      }
    }

    // ---- commit h/c to LDS. gr = [h01,c01,h23,c23] -> h {x,z}, c {y,w}
    {
#pragma unroll
      for (int j = 0; j < 8; j++){
        int row = wave * 4 + (j >> 1);
        int gg  = (j & 1) * 64 + lane;
        *(uint2*)(L + H_S + row * HSTR + gg * 8) = uint2{gr[j].x, gr[j].z};
        *(uint2*)(L + C_S + row * HSTR + gg * 8) = uint2{gr[j].y, gr[j].w};
      }
    }
    __syncthreads();   // B1: H/C committed (all waves past xproj reads of X)

    // ---- U-GEMM + decomp MFMA (Z 0..9); then stage X(t+1) (hides in MFMA)
    {
      f32x4 zA = {0.f,0.f,0.f,0.f}, zB = zA, zD = zA;
#pragma unroll
      for (int kc = 0; kc < 16; kc++){
        bf16x8 a = *(const bf16x8*)(L + H_S + lo * HSTR + kc*64 + hi*16);
        zA = MFMA(a, bP[kc], zA);
        zB = MFMA(a, bQ[kc], zB);
      }
      if (wave >= 2){
#pragma unroll
        for (int kc = 0; kc < 16; kc++){
          bf16x8 a = *(const bf16x8*)(L + C_S + lo * HSTR + kc*64 + hi*16);
          zD = MFMA(a, bR[kc], zD);
        }
      }
      zstore(L, g0*2+nt, lane, zA);
      zstore(L, g1*2+nt, lane, zB);
      if (wave >= 2) zstore(L, 8+nt, lane, zD);
    }
    if (t < T_STEPS - 1){
      char* dst = L + X_S + srow * XSTR + sseg * 32;
#pragma unroll
      for (int j = 0; j < 2; j++){
        float4 a = xv[2*j], b = xv[2*j+1];
        bf16x8 o = { (__bf16)a.x,(__bf16)a.y,(__bf16)a.z,(__bf16)a.w,
                     (__bf16)b.x,(__bf16)b.y,(__bf16)b.z,(__bf16)b.w };
        *(bf16x8*)(dst + j*16) = o;
      }
    }
    __syncthreads();   // B2: Z ready + X(t+1) staged

    // ---- elementwise gate math (fp32); publish tagged u64
    {
      float Tmap = 1.f / __logf(tv + 2.7183f);
      unsigned int hpk = 0, cpk = 0;
      float hv2[2];
#pragma unroll
      for (int e = 0; e < 2; e++){
        int col = ecp + e;
        int ntc = col >> 4, cl = col & 15;
        float zi = zread(L, 0+ntc,  erow, cl) + z2read(L, p2, 0+ntc, erow, cl) + bias_i[e];
        float zf = zread(L, 2+ntc,  erow, cl) + z2read(L, p2, 2+ntc, erow, cl) + bias_f[e];
        float zo = zread(L, 4+ntc,  erow, cl) + z2read(L, p2, 4+ntc, erow, cl) + bias_o[e];
        float zc = zread(L, 6+ntc,  erow, cl) + z2read(L, p2, 6+ntc, erow, cl) + bias_c[e];
        float zdv = zread(L, 8+ntc, erow, cl) + bias_d[e];
        float cst = ftanh(zdv);
        float c1  = cr[e] - cst + Tmap * cst;
        float ig = fsigm(zi), fg = fsigm(zf), og = fsigm(zo);
        float ch = ftanh(zc);
        float c2 = fg * c1 + ig * ch;
        float hv_ = og * ftanh(c2);
        cr[e] = c2; hv2[e] = hv_;
        hpk |= (unsigned int)__builtin_bit_cast(unsigned short, (__bf16)hv_) << (16*e);
        cpk |= (unsigned int)__builtin_bit_cast(unsigned short, (__bf16)c2) << (16*e);
      }
      if (t < T_STEPS - 1){
        const unsigned int wtag  = (unsigned int)((t + 1) & 3);
        const unsigned int tmask = (wtag & 1u) | ((wtag >> 1) << 16);
        hpk = (hpk & 0xFFFEFFFEu) | tmask;   // full tag in both bf16 LSBs
        cpk = (cpk & 0xFFFEFFFEu) | tmask;
        cst8(hcnext + pub_off,
             (unsigned long long)hpk | ((unsigned long long)cpk << 32));
      } else {
        size_t off = (size_t)(rbase + erow) * HID + cbase + ecp;
        P.h_final[off]     = hv2[0];
        P.h_final[off + 1] = hv2[1];
      }
    }
    // no tail barrier: next step's Z2 writes use opposite parity; next step's
    // commit (H/C writes) is after B1-crossing of all waves; X writes at
    // t+1's UGEMM phase are after B1(t+1). EW(t) reads are all pre-B1(t+1).
  }
}

// ---------------- head: out = relu(hT @ fc_w^T + fc_b) @ cls_w^T + cls_b ----
__global__ void __launch_bounds__(256) tlstm_head(const float* __restrict__ hfin,
    const float* __restrict__ fc_w, const float* __restrict__ fc_b,
    const float* __restrict__ cls_w, const float* __restrict__ cls_b,
    float* __restrict__ out)
{
  __shared__ float hrow[512];
  __shared__ float fcv[256];
  const int b = blockIdx.x, tid = threadIdx.x;
  ((float2*)hrow)[tid] = ((const float2*)(hfin + (size_t)b * 512))[tid];
  __syncthreads();
  {
    const float4* w4 = (const float4*)(fc_w + (size_t)tid * 512);
    const float4* h4 = (const float4*)hrow;
    float acc = fc_b[tid];
#pragma unroll 4
    for (int k = 0; k < 128; k++){
      float4 w = w4[k], h = h4[k];
      acc += w.x*h.x + w.y*h.y + w.z*h.z + w.w*h.w;
    }
    fcv[tid] = fmaxf(acc, 0.f);
  }
  __syncthreads();
  const int wave = tid >> 6, lane = tid & 63;
  if (wave < 2){
    const float* cw = cls_w + wave * 256;
    float s = 0.f;
#pragma unroll
    for (int j = lane; j < 256; j += 64) s += fcv[j] * cw[j];
#pragma unroll
    for (int off = 32; off > 0; off >>= 1) s += __shfl_down(s, off, 64);
    if (lane == 0) out[b * 2 + wave] = s + cls_b[wave];
  }
}

// ---------------------------------------------------------------------------
extern "C" void kernel_launch(void* const* d_in, const int* in_sizes, int n_in,
                              void* d_out, int out_size, void* d_ws, size_t ws_size,
                              hipStream_t stream)
{
  (void)in_sizes; (void)n_in; (void)out_size; (void)ws_size;

  ScanP P;
  P.x    = (const float*)d_in[0];
  P.tim  = (const float*)d_in[1];
  P.Wi_w = (const float*)d_in[2];  P.Wi_b = (const float*)d_in[3];
  P.Ui_w = (const float*)d_in[4];  P.Ui_b = (const float*)d_in[5];  P.bi  = (const float*)d_in[6];
  P.Wf_w = (const float*)d_in[7];  P.Wf_b = (const float*)d_in[8];
  P.Uf_w = (const float*)d_in[9];  P.Uf_b = (const float*)d_in[10]; P.bf_ = (const float*)d_in[11];
  P.Wo_w = (const float*)d_in[12]; P.Wo_b = (const float*)d_in[13];
  P.Uo_w = (const float*)d_in[14]; P.Uo_b = (const float*)d_in[15]; P.bo  = (const float*)d_in[16];
  P.Wc_w = (const float*)d_in[17]; P.Wc_b = (const float*)d_in[18];
  P.Uc_w = (const float*)d_in[19]; P.Uc_b = (const float*)d_in[20]; P.bc  = (const float*)d_in[21];
  P.Wd_w = (const float*)d_in[22]; P.b_dec = (const float*)d_in[23];
  const float* fc_w  = (const float*)d_in[24];
  const float* fc_b  = (const float*)d_in[25];
  const float* cls_w = (const float*)d_in[26];
  const float* cls_b = (const float*)d_in[27];

  // workspace layout (identical to R3..R13): [hc_buf 1M][flags 1K][h_final 512K]
  unsigned long long* hc_buf = (unsigned long long*)d_ws;        // 2*256*256 u64
  unsigned int* flags = (unsigned int*)(hc_buf + 2 * BATCH * 256);
  float* h_final = (float*)((char*)flags + 1024);                // 256*512 f32
  P.hc_buf = hc_buf; P.h_final = h_final; P.flags = flags;

  const size_t zero_bytes = (size_t)2 * BATCH * 256 * 8 + 1024;  // hc + flags
  hipMemsetAsync(d_ws, 0, zero_bytes, stream);

  hipLaunchKernelGGL(tlstm_scan, dim3(256), dim3(256), 0, stream, P);
  hipLaunchKernelGGL(tlstm_head, dim3(256), dim3(256), 0, stream,
                     h_final, fc_w, fc_b, cls_w, cls_b, (float*)d_out);
}